// Round 4
// baseline (2410.593 us; speedup 1.0000x reference)
//
#include <hip/hip_runtime.h>
#include <stdint.h>

#define T_STEPS 1024
#define BATCH   512
#define IN_DIM  64
#define HID_DIM 256
#define OUT_DIM 32

// ===========================================================================
// NUMERICS CONTRACT (validated by R4 pass, absmax 7.8e-3 vs 5.75e-2):
//   * dot products: single fp32 accumulator, k ASCENDING, fmaf each step
//   * bias: separately-rounded fp32 add AFTER the chain
//   * LIF: mem = ((0.92f*mem) + cur) - reset, three separate fp32 ops,
//          reset from PREVIOUS mem, compares mem > 1.0f
// Any reassociation flips spikes (binary outputs, 16.7M decisions). Do not.
// ===========================================================================
// LESSON (R2/R3 post-mortem): coalescing is a PER-INSTRUCTION property.
// 8 float4 stores per thread at stride 128B = 64 partial-line touches per
// instruction; TCC does not merge across instructions (measured 495 MB
// written vs 67 MB ideal). A store instruction must cover contiguous full
// lines: transpose through LDS so each wave stores 1 KB contiguous.
// ===========================================================================

#define GLOAD_LDS16(GP, LP)                                                \
    __builtin_amdgcn_global_load_lds(                                      \
        (const __attribute__((address_space(1))) void*)(GP),               \
        (__attribute__((address_space(3))) void*)(LP), 16, 0, 0)

// ---------------------------------------------------------------------------
// Phase 1: fused GEMM1 + LIF1. R1-verified version (390 us, VALUBusy 70%).
// Thread = (b,h); t sequential. W1 row pinned in VGPRs via empty asm.
// x staged through LDS in 32-step chunks, double-buffered, global_load_lds
// width=16 -> prefetch depth 32 steps. Two t-steps interleaved for ILP.
// ---------------------------------------------------------------------------
#define CHUNK 32

__global__ __launch_bounds__(256, 2) void snn_l1(
    const float* __restrict__ x,                  // [T,B,64]
    const float* __restrict__ W1,                 // [256,64]
    const float* __restrict__ b1,                 // [256]
    unsigned long long* __restrict__ bits)        // [T,B,4] u64 ballots
{
    const int b    = blockIdx.x;
    const int h    = threadIdx.x;
    const int wv   = h >> 6;
    const int lane = h & 63;

    __shared__ __align__(16) float xs[2][CHUNK][IN_DIM];   // 2 x 8 KB

    float w1r[IN_DIM];
#pragma unroll
    for (int k = 0; k < IN_DIM; ++k) w1r[k] = W1[h * IN_DIM + k];
    // Pin the row in VGPRs: each asm consumes the loaded value, so the loads
    // cannot be sunk into the t-loop.
#pragma unroll
    for (int k = 0; k < IN_DIM; ++k) asm volatile("" : "+v"(w1r[k]));
    const float bias1 = b1[h];

#define STAGE(BUF, CT)                                                     \
    {                                                                      \
        _Pragma("unroll")                                                  \
        for (int r = 0; r < 2; ++r) {                                      \
            const int slot = (r * 4 + wv) * 64 + lane;                     \
            const int step = slot >> 4;                                    \
            const int f4   = slot & 15;                                    \
            const float4* gp = (const float4*)x +                          \
                ((size_t)((CT) * CHUNK + step) * BATCH + b) * 16 + f4;     \
            GLOAD_LDS16(gp, &xs[BUF][0][0] + slot * 4);                    \
        }                                                                  \
    }

    float mem1 = 0.0f;

    STAGE(0, 0)

    for (int c = 0; c < T_STEPS / CHUNK; ++c) {
        const int cb = c & 1;
        __syncthreads();
        if (c + 1 < T_STEPS / CHUNK) STAGE(cb ^ 1, c + 1)

#pragma unroll
        for (int s = 0; s < CHUNK; s += 2) {
            const float4* xp0 = (const float4*)(&xs[cb][s][0]);
            const float4* xp1 = (const float4*)(&xs[cb][s + 1][0]);
            float acc0 = 0.0f, acc1 = 0.0f;
#pragma unroll
            for (int i = 0; i < 16; ++i) {
                const float4 u = xp0[i];        // broadcast ds_read_b128
                const float4 v = xp1[i];
                acc0 = fmaf(u.x, w1r[4 * i + 0], acc0);
                acc0 = fmaf(u.y, w1r[4 * i + 1], acc0);
                acc0 = fmaf(u.z, w1r[4 * i + 2], acc0);
                acc0 = fmaf(u.w, w1r[4 * i + 3], acc0);
                acc1 = fmaf(v.x, w1r[4 * i + 0], acc1);
                acc1 = fmaf(v.y, w1r[4 * i + 1], acc1);
                acc1 = fmaf(v.z, w1r[4 * i + 2], acc1);
                acc1 = fmaf(v.w, w1r[4 * i + 3], acc1);
            }
            const int t0 = c * CHUNK + s;
            {
                const float cur1 = __fadd_rn(acc0, bias1);
                const float r1 = (mem1 > 1.0f) ? 1.0f : 0.0f;
                mem1 = __fsub_rn(__fadd_rn(__fmul_rn(0.92f, mem1), cur1), r1);
                const unsigned long long bm = __ballot(mem1 > 1.0f);
                if (lane == 0)
                    bits[((size_t)t0 * BATCH + b) * 4 + wv] = bm;
            }
            {
                const float cur1 = __fadd_rn(acc1, bias1);
                const float r1 = (mem1 > 1.0f) ? 1.0f : 0.0f;
                mem1 = __fsub_rn(__fadd_rn(__fmul_rn(0.92f, mem1), cur1), r1);
                const unsigned long long bm = __ballot(mem1 > 1.0f);
                if (lane == 0)
                    bits[((size_t)(t0 + 1) * BATCH + b) * 4 + wv] = bm;
            }
        }
    }
#undef STAGE
}

// ---------------------------------------------------------------------------
// Phase 2: GEMM2. v5: compute unchanged (og fully unrolled, acc[8][4],
// wave-uniform W2 s_loads, exact k-ascending chains). Epilogue now
// TRANSPOSES through LDS so every global store instruction covers 8 full
// contiguous 128-B lines (1 KB/wave/instruction):
//   write: ls[tid][og ^ (tid&7)]   (XOR swizzle -> all 8 bank-groups)
//   read:  wave wv, instr r: slot s = wv*512 + r*64 + lane,
//          row = s>>3, col = (s&7) ^ (row&7)
//   store: cur2_f4[blk*2048 + s]   (contiguous per instruction)
// ---------------------------------------------------------------------------
__global__ __launch_bounds__(256, 4) void snn_l2gemm(
    const uint32_t* __restrict__ bits,   // [T*B, 8] u32
    const float* __restrict__ W2,        // [32,256]
    const float* __restrict__ b2,        // [32]
    float* __restrict__ cur2)            // [T*B, 32]
{
    const int    tid = threadIdx.x;
    const int    wv  = tid >> 6;
    const int    lane = tid & 63;
    const size_t tb  = (size_t)blockIdx.x * 256 + tid;  // 0..T*B-1

    __shared__ __align__(16) float4 ls[256][8];          // 32 KB

    const uint4 wAq = ((const uint4*)bits)[tb * 2 + 0];
    const uint4 wBq = ((const uint4*)bits)[tb * 2 + 1];
    const uint32_t wds[8] = {wAq.x, wAq.y, wAq.z, wAq.w,
                             wBq.x, wBq.y, wBq.z, wBq.w};

#pragma unroll
    for (int og = 0; og < 8; ++og) {
        const float* __restrict__ wr0 = W2 + (og * 4 + 0) * HID_DIM;
        const float* __restrict__ wr1 = W2 + (og * 4 + 1) * HID_DIM;
        const float* __restrict__ wr2 = W2 + (og * 4 + 2) * HID_DIM;
        const float* __restrict__ wr3 = W2 + (og * 4 + 3) * HID_DIM;

        float a0 = 0.0f, a1 = 0.0f, a2 = 0.0f, a3 = 0.0f;

#pragma unroll
        for (int c = 0; c < 16; ++c) {            // 16 chunks x 16 k
            float r0[16], r1[16], r2[16], r3[16];
#pragma unroll
            for (int i = 0; i < 16; ++i) {
                const int k = c * 16 + i;
                r0[i] = wr0[k];                   // wave-uniform -> s_load
                r1[i] = wr1[k];
                r2[i] = wr2[k];
                r3[i] = wr3[k];
            }
            const uint32_t word = wds[c >> 1];    // static after unroll
            const int      base = (c & 1) * 16;
#pragma unroll
            for (int i = 0; i < 16; ++i) {
                const float sf = (float)((word >> (base + i)) & 1u);
                a0 = fmaf(sf, r0[i], a0);         // exact: fl(acc + w) or acc
                a1 = fmaf(sf, r1[i], a1);
                a2 = fmaf(sf, r2[i], a2);
                a3 = fmaf(sf, r3[i], a3);
            }
        }

        // bias (separately rounded), stash into swizzled LDS slot
        const float4 r = make_float4(__fadd_rn(a0, b2[og * 4 + 0]),
                                     __fadd_rn(a1, b2[og * 4 + 1]),
                                     __fadd_rn(a2, b2[og * 4 + 2]),
                                     __fadd_rn(a3, b2[og * 4 + 3]));
        ls[tid][og ^ (tid & 7)] = r;
    }

    __syncthreads();

    // Coalesced writeback: each wave stores its own 8 KB region linearly.
    float4* __restrict__ outp = (float4*)cur2 + (size_t)blockIdx.x * 2048;
#pragma unroll
    for (int r = 0; r < 8; ++r) {
        const int s    = wv * 512 + r * 64 + lane;
        const int row  = s >> 3;
        const int col  = (s & 7) ^ (row & 7);
        outp[s] = ls[row][col];
    }
}

// ---------------------------------------------------------------------------
// Phase 3: LIF2 t-scan. Thread = (b,o), 16384 chains (1 wave/CU ->
// latency-bound). v5: 16-deep load batching to double in-flight requests.
// ---------------------------------------------------------------------------
__global__ __launch_bounds__(256, 4) void snn_l2scan(
    float* __restrict__ spk_io,          // [T,B,32]: cur2 in, spk2 out
    float* __restrict__ mem_out)         // [T,B,32]
{
    const int tid = threadIdx.x;
    const int o   = tid & (OUT_DIM - 1);
    const int b   = blockIdx.x * 8 + (tid >> 5);

    float* p = spk_io  + (size_t)b * OUT_DIM + o;
    float* m = mem_out + (size_t)b * OUT_DIM + o;
    const size_t step = (size_t)BATCH * OUT_DIM;

    float mem2 = 0.0f;
    for (int t = 0; t < T_STEPS; t += 16) {
        float c[16];
#pragma unroll
        for (int u = 0; u < 16; ++u) c[u] = p[(size_t)(t + u) * step];
#pragma unroll
        for (int u = 0; u < 16; ++u) {
            const float r2 = (mem2 > 1.0f) ? 1.0f : 0.0f;
            mem2 = __fsub_rn(__fadd_rn(__fmul_rn(0.92f, mem2), c[u]), r2);
            p[(size_t)(t + u) * step] = (mem2 > 1.0f) ? 1.0f : 0.0f;
            m[(size_t)(t + u) * step] = mem2;
        }
    }
}

extern "C" void kernel_launch(void* const* d_in, const int* in_sizes, int n_in,
                              void* d_out, int out_size, void* d_ws, size_t ws_size,
                              hipStream_t stream) {
    const float* x  = (const float*)d_in[0];  // [T,B,64] fp32
    const float* W1 = (const float*)d_in[1];  // [256,64] fp32
    const float* b1 = (const float*)d_in[2];  // [256]    fp32
    const float* W2 = (const float*)d_in[3];  // [32,256] fp32
    const float* b2 = (const float*)d_in[4];  // [32]     fp32

    float* out_spk = (float*)d_out;                                  // 67 MB
    float* out_mem = out_spk + (size_t)T_STEPS * BATCH * OUT_DIM;    // 67 MB

    // Scratch plan (zero d_ws usage):
    //   bits (16 MB) live at the start of out_mem; consumed entirely by
    //   phase 2 before phase 3 overwrites that region with mem2.
    //   cur2 lives in out_spk; phase 3 overwrites it in-place with spk2.
    unsigned long long* bits = (unsigned long long*)out_mem;

    snn_l1<<<BATCH, 256, 0, stream>>>(x, W1, b1, bits);

    snn_l2gemm<<<T_STEPS * BATCH / 256, 256, 0, stream>>>(
        (const uint32_t*)bits, W2, b2, out_spk);

    snn_l2scan<<<BATCH / 8, 256, 0, stream>>>(out_spk, out_mem);
}

// Round 5
// 1086.698 us; speedup vs baseline: 2.2183x; 2.2183x over previous
//
#include <hip/hip_runtime.h>
#include <stdint.h>

#define T_STEPS 1024
#define BATCH   512
#define IN_DIM  64
#define HID_DIM 256
#define OUT_DIM 32

// ===========================================================================
// NUMERICS CONTRACT (validated by R4 pass, absmax 7.8e-3 vs 5.75e-2):
//   * dot products: single fp32 accumulator, k ASCENDING, fmaf each step
//   * bias: separately-rounded fp32 add AFTER the chain
//   * LIF: mem = ((0.92f*mem) + cur) - reset, three separate fp32 ops,
//          reset from PREVIOUS mem, compares mem > 1.0f
// Any reassociation flips spikes (binary outputs, 16.7M decisions). Do not.
// ===========================================================================
// LESSONS (R2-R4 post-mortems), phase 2 specifically:
//  * cur2 (67 MB) is L3-resident; partial-line RMW mostly stays in L3.
//  * A store site INSIDE the unrolled og-loop (global in R2, LDS in v5)
//    triggers per-thread scratch spills: ~4.8 GB HBM traffic, 3-4x slower.
//    ALL stores must be in the epilogue after all compute (v4 = clean).
//  * Coalescing is per-instruction: one store instr must cover contiguous
//    full 128-B lines. v4's stride-128 16-B epilogue stores still cost
//    ~500 MB HBM write; fix = LDS transpose in the epilogue only.
// ===========================================================================

#define GLOAD_LDS16(GP, LP)                                                \
    __builtin_amdgcn_global_load_lds(                                      \
        (const __attribute__((address_space(1))) void*)(GP),               \
        (__attribute__((address_space(3))) void*)(LP), 16, 0, 0)

// ---------------------------------------------------------------------------
// Phase 1: fused GEMM1 + LIF1. R1-verified version (390 us, VALUBusy 70%).
// Thread = (b,h); t sequential. W1 row pinned in VGPRs via empty asm.
// x staged through LDS in 32-step chunks, double-buffered, global_load_lds
// width=16 -> prefetch depth 32 steps. Two t-steps interleaved for ILP.
// ---------------------------------------------------------------------------
#define CHUNK 32

__global__ __launch_bounds__(256, 2) void snn_l1(
    const float* __restrict__ x,                  // [T,B,64]
    const float* __restrict__ W1,                 // [256,64]
    const float* __restrict__ b1,                 // [256]
    unsigned long long* __restrict__ bits)        // [T,B,4] u64 ballots
{
    const int b    = blockIdx.x;
    const int h    = threadIdx.x;
    const int wv   = h >> 6;
    const int lane = h & 63;

    __shared__ __align__(16) float xs[2][CHUNK][IN_DIM];   // 2 x 8 KB

    float w1r[IN_DIM];
#pragma unroll
    for (int k = 0; k < IN_DIM; ++k) w1r[k] = W1[h * IN_DIM + k];
    // Pin the row in VGPRs: each asm consumes the loaded value, so the loads
    // cannot be sunk into the t-loop.
#pragma unroll
    for (int k = 0; k < IN_DIM; ++k) asm volatile("" : "+v"(w1r[k]));
    const float bias1 = b1[h];

#define STAGE(BUF, CT)                                                     \
    {                                                                      \
        _Pragma("unroll")                                                  \
        for (int r = 0; r < 2; ++r) {                                      \
            const int slot = (r * 4 + wv) * 64 + lane;                     \
            const int step = slot >> 4;                                    \
            const int f4   = slot & 15;                                    \
            const float4* gp = (const float4*)x +                          \
                ((size_t)((CT) * CHUNK + step) * BATCH + b) * 16 + f4;     \
            GLOAD_LDS16(gp, &xs[BUF][0][0] + slot * 4);                    \
        }                                                                  \
    }

    float mem1 = 0.0f;

    STAGE(0, 0)

    for (int c = 0; c < T_STEPS / CHUNK; ++c) {
        const int cb = c & 1;
        __syncthreads();
        if (c + 1 < T_STEPS / CHUNK) STAGE(cb ^ 1, c + 1)

#pragma unroll
        for (int s = 0; s < CHUNK; s += 2) {
            const float4* xp0 = (const float4*)(&xs[cb][s][0]);
            const float4* xp1 = (const float4*)(&xs[cb][s + 1][0]);
            float acc0 = 0.0f, acc1 = 0.0f;
#pragma unroll
            for (int i = 0; i < 16; ++i) {
                const float4 u = xp0[i];        // broadcast ds_read_b128
                const float4 v = xp1[i];
                acc0 = fmaf(u.x, w1r[4 * i + 0], acc0);
                acc0 = fmaf(u.y, w1r[4 * i + 1], acc0);
                acc0 = fmaf(u.z, w1r[4 * i + 2], acc0);
                acc0 = fmaf(u.w, w1r[4 * i + 3], acc0);
                acc1 = fmaf(v.x, w1r[4 * i + 0], acc1);
                acc1 = fmaf(v.y, w1r[4 * i + 1], acc1);
                acc1 = fmaf(v.z, w1r[4 * i + 2], acc1);
                acc1 = fmaf(v.w, w1r[4 * i + 3], acc1);
            }
            const int t0 = c * CHUNK + s;
            {
                const float cur1 = __fadd_rn(acc0, bias1);
                const float r1 = (mem1 > 1.0f) ? 1.0f : 0.0f;
                mem1 = __fsub_rn(__fadd_rn(__fmul_rn(0.92f, mem1), cur1), r1);
                const unsigned long long bm = __ballot(mem1 > 1.0f);
                if (lane == 0)
                    bits[((size_t)t0 * BATCH + b) * 4 + wv] = bm;
            }
            {
                const float cur1 = __fadd_rn(acc1, bias1);
                const float r1 = (mem1 > 1.0f) ? 1.0f : 0.0f;
                mem1 = __fsub_rn(__fadd_rn(__fmul_rn(0.92f, mem1), cur1), r1);
                const unsigned long long bm = __ballot(mem1 > 1.0f);
                if (lane == 0)
                    bits[((size_t)(t0 + 1) * BATCH + b) * 4 + wv] = bm;
            }
        }
    }
#undef STAGE
}

// ---------------------------------------------------------------------------
// Phase 2: GEMM2. v6 = v4's compute VERBATIM (og fully unrolled, acc[8][4],
// wave-uniform W2 s_loads, exact k-ascending chains, NO store inside the og
// loop -- the spill trigger), plus an epilogue-only LDS transpose so each
// global store instruction covers 8 full contiguous 128-B lines:
//   write: ls[tid][og ^ (tid&7)]   (XOR swizzle spreads the 8 bank-groups)
//   read:  slot s = wv*512 + r*64 + lane; row = s>>3; col = (s&7)^(row&7)
//   store: cur2_f4[blk*2048 + s]   (64 lanes x 16 B contiguous)
// ---------------------------------------------------------------------------
__global__ __launch_bounds__(256, 4) void snn_l2gemm(
    const uint32_t* __restrict__ bits,   // [T*B, 8] u32
    const float* __restrict__ W2,        // [32,256]
    const float* __restrict__ b2,        // [32]
    float* __restrict__ cur2)            // [T*B, 32]
{
    const int    tid  = threadIdx.x;
    const int    wv   = tid >> 6;
    const int    lane = tid & 63;
    const size_t tb   = (size_t)blockIdx.x * 256 + tid;  // 0..T*B-1

    __shared__ __align__(16) float4 ls[256][8];          // 32 KB

    const uint4 wAq = ((const uint4*)bits)[tb * 2 + 0];
    const uint4 wBq = ((const uint4*)bits)[tb * 2 + 1];
    const uint32_t wds[8] = {wAq.x, wAq.y, wAq.z, wAq.w,
                             wBq.x, wBq.y, wBq.z, wBq.w};

    float acc[8][4];

#pragma unroll
    for (int og = 0; og < 8; ++og) {
        const float* __restrict__ wr0 = W2 + (og * 4 + 0) * HID_DIM;
        const float* __restrict__ wr1 = W2 + (og * 4 + 1) * HID_DIM;
        const float* __restrict__ wr2 = W2 + (og * 4 + 2) * HID_DIM;
        const float* __restrict__ wr3 = W2 + (og * 4 + 3) * HID_DIM;

        float a0 = 0.0f, a1 = 0.0f, a2 = 0.0f, a3 = 0.0f;

#pragma unroll
        for (int c = 0; c < 16; ++c) {            // 16 chunks x 16 k
            float r0[16], r1[16], r2[16], r3[16];
#pragma unroll
            for (int i = 0; i < 16; ++i) {
                const int k = c * 16 + i;
                r0[i] = wr0[k];                   // wave-uniform -> s_load
                r1[i] = wr1[k];
                r2[i] = wr2[k];
                r3[i] = wr3[k];
            }
            const uint32_t word = wds[c >> 1];    // static after unroll
            const int      base = (c & 1) * 16;
#pragma unroll
            for (int i = 0; i < 16; ++i) {
                const float sf = (float)((word >> (base + i)) & 1u);
                a0 = fmaf(sf, r0[i], a0);         // exact: fl(acc + w) or acc
                a1 = fmaf(sf, r1[i], a1);
                a2 = fmaf(sf, r2[i], a2);
                a3 = fmaf(sf, r3[i], a3);
            }
        }

        acc[og][0] = a0;  acc[og][1] = a1;
        acc[og][2] = a2;  acc[og][3] = a3;
    }

    // ---- Epilogue only: bias, LDS transpose, coalesced full-line stores ----
#pragma unroll
    for (int og = 0; og < 8; ++og) {
        const float4 r = make_float4(__fadd_rn(acc[og][0], b2[og * 4 + 0]),
                                     __fadd_rn(acc[og][1], b2[og * 4 + 1]),
                                     __fadd_rn(acc[og][2], b2[og * 4 + 2]),
                                     __fadd_rn(acc[og][3], b2[og * 4 + 3]));
        ls[tid][og ^ (tid & 7)] = r;
    }

    __syncthreads();

    float4* __restrict__ outp = (float4*)cur2 + (size_t)blockIdx.x * 2048;
#pragma unroll
    for (int r = 0; r < 8; ++r) {
        const int s   = wv * 512 + r * 64 + lane;
        const int row = s >> 3;
        const int col = (s & 7) ^ (row & 7);
        outp[s] = ls[row][col];                   // 1 KB contiguous per instr
    }
}

// ---------------------------------------------------------------------------
// Phase 3: LIF2 t-scan. Thread = (b,o), 16384 chains (1 wave/SIMD ->
// latency-bound). 16-deep load batching to double in-flight requests.
// ---------------------------------------------------------------------------
__global__ __launch_bounds__(256, 4) void snn_l2scan(
    float* __restrict__ spk_io,          // [T,B,32]: cur2 in, spk2 out
    float* __restrict__ mem_out)         // [T,B,32]
{
    const int tid = threadIdx.x;
    const int o   = tid & (OUT_DIM - 1);
    const int b   = blockIdx.x * 8 + (tid >> 5);

    float* p = spk_io  + (size_t)b * OUT_DIM + o;
    float* m = mem_out + (size_t)b * OUT_DIM + o;
    const size_t step = (size_t)BATCH * OUT_DIM;

    float mem2 = 0.0f;
    for (int t = 0; t < T_STEPS; t += 16) {
        float c[16];
#pragma unroll
        for (int u = 0; u < 16; ++u) c[u] = p[(size_t)(t + u) * step];
#pragma unroll
        for (int u = 0; u < 16; ++u) {
            const float r2 = (mem2 > 1.0f) ? 1.0f : 0.0f;
            mem2 = __fsub_rn(__fadd_rn(__fmul_rn(0.92f, mem2), c[u]), r2);
            p[(size_t)(t + u) * step] = (mem2 > 1.0f) ? 1.0f : 0.0f;
            m[(size_t)(t + u) * step] = mem2;
        }
    }
}

extern "C" void kernel_launch(void* const* d_in, const int* in_sizes, int n_in,
                              void* d_out, int out_size, void* d_ws, size_t ws_size,
                              hipStream_t stream) {
    const float* x  = (const float*)d_in[0];  // [T,B,64] fp32
    const float* W1 = (const float*)d_in[1];  // [256,64] fp32
    const float* b1 = (const float*)d_in[2];  // [256]    fp32
    const float* W2 = (const float*)d_in[3];  // [32,256] fp32
    const float* b2 = (const float*)d_in[4];  // [32]     fp32

    float* out_spk = (float*)d_out;                                  // 67 MB
    float* out_mem = out_spk + (size_t)T_STEPS * BATCH * OUT_DIM;    // 67 MB

    // Scratch plan (zero d_ws usage):
    //   bits (16 MB) live at the start of out_mem; consumed entirely by
    //   phase 2 before phase 3 overwrites that region with mem2.
    //   cur2 lives in out_spk; phase 3 overwrites it in-place with spk2.
    unsigned long long* bits = (unsigned long long*)out_mem;

    snn_l1<<<BATCH, 256, 0, stream>>>(x, W1, b1, bits);

    snn_l2gemm<<<T_STEPS * BATCH / 256, 256, 0, stream>>>(
        (const uint32_t*)bits, W2, b2, out_spk);

    snn_l2scan<<<BATCH / 8, 256, 0, stream>>>(out_spk, out_mem);
}

// Round 6
// 780.038 us; speedup vs baseline: 3.0904x; 1.3931x over previous
//
#include <hip/hip_runtime.h>
#include <stdint.h>

#define T_STEPS 1024
#define BATCH   512
#define IN_DIM  64
#define HID_DIM 256
#define OUT_DIM 32

// ===========================================================================
// NUMERICS CONTRACT (validated, absmax 7.8e-3 vs 5.75e-2):
//   * dot products: single fp32 accumulator, k ASCENDING, fmaf each step
//   * bias: separately-rounded fp32 add AFTER the chain
//   * LIF: mem = ((0.92f*mem) + cur) - reset, three separate fp32 ops,
//          reset from PREVIOUS mem, compares mem > 1.0f
// Any reassociation flips spikes (binary outputs, 16.7M decisions). Do not.
// ===========================================================================
// LESSONS (R2-R5 post-mortems), phase 2 specifically:
//  * Split-og (grid.y, few outputs/thread, millions of short threads) is the
//    measured-best structure: 389 us for phase2+3 combined (R1).
//  * Merging all 8 og into one thread produced ~500 MB phantom HBM WRITE
//    (cause unidentified; NOT partial-line coalescing: v6's fully-coalesced
//    stores showed the same 515 MB. l1's scattered 8-B stores show ZERO
//    amplification -> L3 merges partial lines fine).
//  * Do not put stores inside the unrolled og loop (R2/v5: 4.8 GB scratch).
//  * This round: og-PAIRS (grid.y=4) -- minimal delta from split-8; extract
//    amortized over 8 fmas, bits re-reads halved, stores epilogue-only.
// ===========================================================================

#define GLOAD_LDS16(GP, LP)                                                \
    __builtin_amdgcn_global_load_lds(                                      \
        (const __attribute__((address_space(1))) void*)(GP),               \
        (__attribute__((address_space(3))) void*)(LP), 16, 0, 0)

// ---------------------------------------------------------------------------
// Phase 1: fused GEMM1 + LIF1. R1-verified version (390 us, VALUBusy 70%).
// Thread = (b,h); t sequential. W1 row pinned in VGPRs via empty asm.
// x staged through LDS in 32-step chunks, double-buffered, global_load_lds
// width=16 -> prefetch depth 32 steps. Two t-steps interleaved for ILP.
// Structural floor analysis: per wave per t = 64 fma + 16 ds_read_b128
// (broadcast) + ~15 misc at 2 waves/SIMD -> ~390 us is near the balanced
// issue/LDS bound for this decomposition. Do not touch without isolation.
// ---------------------------------------------------------------------------
#define CHUNK 32

__global__ __launch_bounds__(256, 2) void snn_l1(
    const float* __restrict__ x,                  // [T,B,64]
    const float* __restrict__ W1,                 // [256,64]
    const float* __restrict__ b1,                 // [256]
    unsigned long long* __restrict__ bits)        // [T,B,4] u64 ballots
{
    const int b    = blockIdx.x;
    const int h    = threadIdx.x;
    const int wv   = h >> 6;
    const int lane = h & 63;

    __shared__ __align__(16) float xs[2][CHUNK][IN_DIM];   // 2 x 8 KB

    float w1r[IN_DIM];
#pragma unroll
    for (int k = 0; k < IN_DIM; ++k) w1r[k] = W1[h * IN_DIM + k];
    // Pin the row in VGPRs: each asm consumes the loaded value, so the loads
    // cannot be sunk into the t-loop.
#pragma unroll
    for (int k = 0; k < IN_DIM; ++k) asm volatile("" : "+v"(w1r[k]));
    const float bias1 = b1[h];

#define STAGE(BUF, CT)                                                     \
    {                                                                      \
        _Pragma("unroll")                                                  \
        for (int r = 0; r < 2; ++r) {                                      \
            const int slot = (r * 4 + wv) * 64 + lane;                     \
            const int step = slot >> 4;                                    \
            const int f4   = slot & 15;                                    \
            const float4* gp = (const float4*)x +                          \
                ((size_t)((CT) * CHUNK + step) * BATCH + b) * 16 + f4;     \
            GLOAD_LDS16(gp, &xs[BUF][0][0] + slot * 4);                    \
        }                                                                  \
    }

    float mem1 = 0.0f;

    STAGE(0, 0)

    for (int c = 0; c < T_STEPS / CHUNK; ++c) {
        const int cb = c & 1;
        __syncthreads();
        if (c + 1 < T_STEPS / CHUNK) STAGE(cb ^ 1, c + 1)

#pragma unroll
        for (int s = 0; s < CHUNK; s += 2) {
            const float4* xp0 = (const float4*)(&xs[cb][s][0]);
            const float4* xp1 = (const float4*)(&xs[cb][s + 1][0]);
            float acc0 = 0.0f, acc1 = 0.0f;
#pragma unroll
            for (int i = 0; i < 16; ++i) {
                const float4 u = xp0[i];        // broadcast ds_read_b128
                const float4 v = xp1[i];
                acc0 = fmaf(u.x, w1r[4 * i + 0], acc0);
                acc0 = fmaf(u.y, w1r[4 * i + 1], acc0);
                acc0 = fmaf(u.z, w1r[4 * i + 2], acc0);
                acc0 = fmaf(u.w, w1r[4 * i + 3], acc0);
                acc1 = fmaf(v.x, w1r[4 * i + 0], acc1);
                acc1 = fmaf(v.y, w1r[4 * i + 1], acc1);
                acc1 = fmaf(v.z, w1r[4 * i + 2], acc1);
                acc1 = fmaf(v.w, w1r[4 * i + 3], acc1);
            }
            const int t0 = c * CHUNK + s;
            {
                const float cur1 = __fadd_rn(acc0, bias1);
                const float r1 = (mem1 > 1.0f) ? 1.0f : 0.0f;
                mem1 = __fsub_rn(__fadd_rn(__fmul_rn(0.92f, mem1), cur1), r1);
                const unsigned long long bm = __ballot(mem1 > 1.0f);
                if (lane == 0)
                    bits[((size_t)t0 * BATCH + b) * 4 + wv] = bm;
            }
            {
                const float cur1 = __fadd_rn(acc1, bias1);
                const float r1 = (mem1 > 1.0f) ? 1.0f : 0.0f;
                mem1 = __fsub_rn(__fadd_rn(__fmul_rn(0.92f, mem1), cur1), r1);
                const unsigned long long bm = __ballot(mem1 > 1.0f);
                if (lane == 0)
                    bits[((size_t)(t0 + 1) * BATCH + b) * 4 + wv] = bm;
            }
        }
    }
#undef STAGE
}

// ---------------------------------------------------------------------------
// Phase 2: GEMM2, og-PAIR split. Lane = one (t,b); blockIdx.y = og2 (0..3)
// selects outputs o = og2*8 .. og2*8+7. Same structure as the R1-verified
// split-8 kernel (high TLP, stores only in epilogue, partial lines absorbed
// by L3) but each bit-extract now feeds 8 fmas instead of 4, and bits are
// re-read 4x instead of 8x. W2 tile chunked 8k-at-a-time so the wave-uniform
// scalar tile stays <= 64 SGPRs. Exact k-ascending chain per output.
// ---------------------------------------------------------------------------
__global__ __launch_bounds__(256, 4) void snn_l2gemm(
    const uint32_t* __restrict__ bits,   // [T*B, 8] u32
    const float* __restrict__ W2,        // [32,256]
    const float* __restrict__ b2,        // [32]
    float* __restrict__ cur2)            // [T*B, 32]
{
    const int    og2 = blockIdx.y;                             // 0..3
    const int    ob  = og2 * 8;                                // output base
    const size_t tb  = (size_t)blockIdx.x * 256 + threadIdx.x; // 0..T*B-1

    const uint4 wAq = ((const uint4*)bits)[tb * 2 + 0];
    const uint4 wBq = ((const uint4*)bits)[tb * 2 + 1];
    const uint32_t wds[8] = {wAq.x, wAq.y, wAq.z, wAq.w,
                             wBq.x, wBq.y, wBq.z, wBq.w};

    const float* __restrict__ wr0 = W2 + (ob + 0) * HID_DIM;
    const float* __restrict__ wr1 = W2 + (ob + 1) * HID_DIM;
    const float* __restrict__ wr2 = W2 + (ob + 2) * HID_DIM;
    const float* __restrict__ wr3 = W2 + (ob + 3) * HID_DIM;
    const float* __restrict__ wr4 = W2 + (ob + 4) * HID_DIM;
    const float* __restrict__ wr5 = W2 + (ob + 5) * HID_DIM;
    const float* __restrict__ wr6 = W2 + (ob + 6) * HID_DIM;
    const float* __restrict__ wr7 = W2 + (ob + 7) * HID_DIM;

    float a0 = 0.0f, a1 = 0.0f, a2 = 0.0f, a3 = 0.0f;
    float a4 = 0.0f, a5 = 0.0f, a6 = 0.0f, a7 = 0.0f;

#pragma unroll
    for (int c = 0; c < 32; ++c) {            // 32 chunks x 8 k
        float r0[8], r1[8], r2[8], r3[8], r4[8], r5[8], r6[8], r7[8];
#pragma unroll
        for (int i = 0; i < 8; ++i) {
            const int k = c * 8 + i;
            r0[i] = wr0[k];                   // wave-uniform -> s_load
            r1[i] = wr1[k];
            r2[i] = wr2[k];
            r3[i] = wr3[k];
            r4[i] = wr4[k];
            r5[i] = wr5[k];
            r6[i] = wr6[k];
            r7[i] = wr7[k];
        }
        const uint32_t word = wds[c >> 2];    // static after unroll
        const int      base = (c & 3) * 8;
#pragma unroll
        for (int i = 0; i < 8; ++i) {
            const float sf = (float)((word >> (base + i)) & 1u);  // 0.0/1.0
            a0 = fmaf(sf, r0[i], a0);         // exact: fl(acc + w) or acc
            a1 = fmaf(sf, r1[i], a1);
            a2 = fmaf(sf, r2[i], a2);
            a3 = fmaf(sf, r3[i], a3);
            a4 = fmaf(sf, r4[i], a4);
            a5 = fmaf(sf, r5[i], a5);
            a6 = fmaf(sf, r6[i], a6);
            a7 = fmaf(sf, r7[i], a7);
        }
    }

    // Epilogue only: separately-rounded bias adds, two back-to-back float4
    // stores (32 B contiguous per lane).
    const float4 lo = make_float4(__fadd_rn(a0, b2[ob + 0]),
                                  __fadd_rn(a1, b2[ob + 1]),
                                  __fadd_rn(a2, b2[ob + 2]),
                                  __fadd_rn(a3, b2[ob + 3]));
    const float4 hi = make_float4(__fadd_rn(a4, b2[ob + 4]),
                                  __fadd_rn(a5, b2[ob + 5]),
                                  __fadd_rn(a6, b2[ob + 6]),
                                  __fadd_rn(a7, b2[ob + 7]));
    float4* outp = (float4*)cur2 + tb * (OUT_DIM / 4) + og2 * 2;
    outp[0] = lo;
    outp[1] = hi;
}

// ---------------------------------------------------------------------------
// Phase 3: LIF2 t-scan. R1-verified version. Thread = (b,o), 16384 chains.
// Reads cur2 in-place from the out_spk region and overwrites it with spk2;
// mem2 to out_mem. 8-deep load batching.
// ---------------------------------------------------------------------------
__global__ __launch_bounds__(256, 4) void snn_l2scan(
    float* __restrict__ spk_io,          // [T,B,32]: cur2 in, spk2 out
    float* __restrict__ mem_out)         // [T,B,32]
{
    const int tid = threadIdx.x;
    const int o   = tid & (OUT_DIM - 1);
    const int b   = blockIdx.x * 8 + (tid >> 5);

    float* p = spk_io  + (size_t)b * OUT_DIM + o;
    float* m = mem_out + (size_t)b * OUT_DIM + o;
    const size_t step = (size_t)BATCH * OUT_DIM;

    float mem2 = 0.0f;
    for (int t = 0; t < T_STEPS; t += 8) {
        float c[8];
#pragma unroll
        for (int u = 0; u < 8; ++u) c[u] = p[(size_t)(t + u) * step];
#pragma unroll
        for (int u = 0; u < 8; ++u) {
            const float r2 = (mem2 > 1.0f) ? 1.0f : 0.0f;
            mem2 = __fsub_rn(__fadd_rn(__fmul_rn(0.92f, mem2), c[u]), r2);
            p[(size_t)(t + u) * step] = (mem2 > 1.0f) ? 1.0f : 0.0f;
            m[(size_t)(t + u) * step] = mem2;
        }
    }
}

extern "C" void kernel_launch(void* const* d_in, const int* in_sizes, int n_in,
                              void* d_out, int out_size, void* d_ws, size_t ws_size,
                              hipStream_t stream) {
    const float* x  = (const float*)d_in[0];  // [T,B,64] fp32
    const float* W1 = (const float*)d_in[1];  // [256,64] fp32
    const float* b1 = (const float*)d_in[2];  // [256]    fp32
    const float* W2 = (const float*)d_in[3];  // [32,256] fp32
    const float* b2 = (const float*)d_in[4];  // [32]     fp32

    float* out_spk = (float*)d_out;                                  // 67 MB
    float* out_mem = out_spk + (size_t)T_STEPS * BATCH * OUT_DIM;    // 67 MB

    // Scratch plan (zero d_ws usage):
    //   bits (16 MB) live at the start of out_mem; consumed entirely by
    //   phase 2 before phase 3 overwrites that region with mem2.
    //   cur2 lives in out_spk; phase 3 overwrites it in-place with spk2.
    unsigned long long* bits = (unsigned long long*)out_mem;

    snn_l1<<<BATCH, 256, 0, stream>>>(x, W1, b1, bits);

    dim3 g2(T_STEPS * BATCH / 256, 4);
    snn_l2gemm<<<g2, 256, 0, stream>>>((const uint32_t*)bits, W2, b2, out_spk);

    snn_l2scan<<<BATCH / 8, 256, 0, stream>>>(out_spk, out_mem);
}